// Round 9
// baseline (12254.215 us; speedup 1.0000x reference)
//
#include <hip/hip_runtime.h>
#include <hip/hip_bf16.h>
#include <stdint.h>

#define UNITS 400
#define GATES 1600
#define TLEN  1000
#define BATCH 64

#define NBLK 25        // blocks per group (16 units each)
#define NGRP 8         // groups; blockIdx = j*NGRP+gr -> group is XCD-local
#define BPG  8         // batches per group
#define UPB  16        // units per block
#define CPB  64        // cols per block (4 gates x 16 units)
#define KK   25        // k-split
#define KCH  16        // k per z-thread -> wr[16][4] = 64 floats (fits VGPR)
#define ZP   68        // zpart pad: 68*4B row stride (16B aligned, low conflict)

// d_ws layout (tiny now: no part buffer)
#define WBUF_OFF 0
#define WBUF_SZ  (NBLK*UNITS*CPB*4)      // 2,560,000
#define HBUF_OFF (WBUF_OFF + WBUF_SZ)
#define HBUF_SZ  (2*UNITS*BATCH*8)       //   409,600 (u64 packets, [p][u][b])
#define WS_FULL  ((size_t)(HBUF_OFF + HBUF_SZ))

__device__ __forceinline__ float sigmoid_(float x) {
    return 1.0f / (1.0f + __expf(-x));
}
__device__ __forceinline__ float tanh_(float x) {
    return 1.0f - 2.0f / (__expf(2.0f * x) + 1.0f);
}

// ---- one-time reorder: wbuf[j][k][c] = W_h[k][(c/16)*400 + j*16 + c%16] ----
__global__ void reorder_w(const float* __restrict__ W_h, float* __restrict__ wbuf) {
    int i = blockIdx.x * 256 + threadIdx.x;
    if (i >= NBLK * UNITS * CPB) return;
    int c = i % CPB;
    int k = (i / CPB) % UNITS;
    int j = i / (CPB * UNITS);
    int col = (c / UPB) * UNITS + j * UPB + (c % UPB);
    wbuf[i] = W_h[k * GATES + col];
}

__global__ __launch_bounds__(512, 1) void lstm_mb(
    const float* __restrict__ x,      // [B,T,3]
    const float* __restrict__ W_x,    // [3,1600]
    const float* __restrict__ bvec,   // [1600]
    const float* __restrict__ p_i,
    const float* __restrict__ p_f,
    const float* __restrict__ p_o,
    const float* __restrict__ W_out,  // [400,3]
    const float* __restrict__ b_out,  // [3]
    const float* __restrict__ wbuf,
    unsigned long long* __restrict__ hbuf,   // [2][U][B] {tag,val}
    float* __restrict__ out)                 // [B,T,3]
{
    const int gr  = blockIdx.x % NGRP;   // all 25 blocks of a group share an XCD
    const int j   = blockIdx.x / NGRP;
    const int tid = threadIdx.x;

    __shared__ float hsh[BPG][UNITS];        // 12.8 KB (full h for 8 batches)
    __shared__ float zpart[KK][BPG][ZP];     // 54.4 KB
    __shared__ float wosh[UNITS][3];         //  4.8 KB (full W_out)
    __shared__ float xsh[BPG][4];
    __shared__ float yred[3][4];

    // ---- roles ----
    const int  kk = tid / UPB, cq = tid % UPB;   // z-role: tid < 400
    const bool zrole = (tid < KK * UPB);
    const int  k0 = kk * KCH;

    const int  gb = tid & 7, gu = tid >> 3;      // gate-role: tid < 128
    const bool grole = (tid < BPG * UPB);

    // ---- register-pinned weight patch: 16x4 floats ----
    float wr[KCH][4];
    if (zrole) {
        const float* wslice = wbuf + (size_t)j * UNITS * CPB;
        #pragma unroll
        for (int r = 0; r < KCH; ++r) {
            const float4 w = *(const float4*)&wslice[(size_t)(k0 + r) * CPB + cq * 4];
            wr[r][0] = w.x; wr[r][1] = w.y; wr[r][2] = w.z; wr[r][3] = w.w;
        }
        #pragma unroll
        for (int r = 0; r < KCH; ++r)
            asm volatile("" : "+v"(wr[r][0]), "+v"(wr[r][1]),
                              "+v"(wr[r][2]), "+v"(wr[r][3]));
    }

    // ---- gate-thread hoists ----
    int unit = 0, batch = 0;
    float wxr[3][4], bbv[4];
    float piu = 0.f, pfu = 0.f, pou = 0.f, cc = 0.f;
    if (grole) {
        unit  = j * UPB + gu;
        batch = gr * BPG + gb;
        #pragma unroll
        for (int g = 0; g < 4; ++g) {
            const int gcol = g * UNITS + unit;
            wxr[0][g] = W_x[gcol];
            wxr[1][g] = W_x[GATES + gcol];
            wxr[2][g] = W_x[2 * GATES + gcol];
            bbv[g]    = bvec[gcol];
        }
        piu = p_i[unit]; pfu = p_f[unit]; pou = p_o[unit];
    }
    if (tid < UNITS) {
        wosh[tid][0] = W_out[tid * 3 + 0];
        wosh[tid][1] = W_out[tid * 3 + 1];
        wosh[tid][2] = W_out[tid * 3 + 2];
        #pragma unroll
        for (int b = 0; b < BPG; ++b) hsh[b][tid] = 0.f;
    }
    __syncthreads();

#define ZFMA(hv, r)                                   \
    a.x = fmaf(hv, wr[r][0], a.x);                    \
    a.y = fmaf(hv, wr[r][1], a.y);                    \
    a.z = fmaf(hv, wr[r][2], a.z);                    \
    a.w = fmaf(hv, wr[r][3], a.w);

    for (int t = 0; t < TLEN; ++t) {
        const int p = t & 1;

        // ================= A: z-partials / y for t-1 / x stage ==================
        if (zrole) {
            #pragma unroll
            for (int b = 0; b < BPG; ++b) {
                const float4 h0 = *(const float4*)&hsh[b][k0];
                const float4 h1 = *(const float4*)&hsh[b][k0 + 4];
                const float4 h2 = *(const float4*)&hsh[b][k0 + 8];
                const float4 h3 = *(const float4*)&hsh[b][k0 + 12];
                float4 a = {0.f, 0.f, 0.f, 0.f};
                ZFMA(h0.x,  0) ZFMA(h0.y,  1) ZFMA(h0.z,  2) ZFMA(h0.w,  3)
                ZFMA(h1.x,  4) ZFMA(h1.y,  5) ZFMA(h1.z,  6) ZFMA(h1.w,  7)
                ZFMA(h2.x,  8) ZFMA(h2.y,  9) ZFMA(h2.z, 10) ZFMA(h2.w, 11)
                ZFMA(h3.x, 12) ZFMA(h3.y, 13) ZFMA(h3.z, 14) ZFMA(h3.w, 15)
                *(float4*)&zpart[kk][b][cq * 4] = a;
            }
        } else if (tid >= 400 && tid < 412) {
            if (j < BPG && t > 0) {
                // y partial for step t-1: hsh holds h_{t-1} (full, all batches)
                const int f = (tid - 400) >> 2, ch = (tid - 400) & 3;
                float s = 0.f;
                const int u0 = ch * 100;
                #pragma unroll 4
                for (int u = u0; u < u0 + 100; ++u)
                    s += hsh[j][u] * wosh[u][f];
                yred[f][ch] = s;
            }
        } else if (tid >= 424 && tid < 424 + BPG * 3) {
            const int b = (tid - 424) / 3, f = (tid - 424) % 3;
            xsh[b][f] = x[((size_t)(gr * BPG + b) * TLEN + t) * 3 + f];
        }
        __syncthreads();   // zpart/xsh/yred ready; hsh reads done

        // ================= B: gates + publish  ∥  C: y-write + poll =============
        if (grole) {
            const float x0 = xsh[gb][0], x1 = xsh[gb][1], x2 = xsh[gb][2];
            float s[4];
            #pragma unroll
            for (int g = 0; g < 4; ++g) {
                float acc = fmaf(x0, wxr[0][g],
                            fmaf(x1, wxr[1][g],
                            fmaf(x2, wxr[2][g], bbv[g])));
                #pragma unroll
                for (int q = 0; q < KK; ++q) acc += zpart[q][gb][g * UPB + gu];
                s[g] = acc;
            }
            const float ig = sigmoid_(fmaf(piu, cc, s[0]));
            const float fg = sigmoid_(fmaf(pfu, cc, s[1]));
            const float gg = tanh_(s[2]);
            const float cn = fmaf(fg, cc, ig * gg);
            const float og = sigmoid_(fmaf(pou, cn, s[3]));
            const float hn = og * tanh_(cn);
            cc = cn;
            hsh[gb][unit] = hn;   // own slice locally
            const unsigned long long pkt =
                ((unsigned long long)(unsigned)(t + 1) << 32) |
                (unsigned long long)__float_as_uint(hn);
            __hip_atomic_store(&hbuf[(size_t)p * UNITS * BATCH + (size_t)unit * BATCH + batch],
                               pkt, __ATOMIC_RELAXED, __HIP_MEMORY_SCOPE_AGENT);
        } else {
            // y final write for t-1 (3 threads of blocks j<8; off critical path)
            if (t > 0 && j < BPG && tid < 131) {
                const int f = tid - 128;
                out[((size_t)(gr * BPG + j) * TLEN + (t - 1)) * 3 + f] =
                    b_out[f] + yred[f][0] + yred[f][1] + yred[f][2] + yred[f][3];
            }
            // poll: one unit (skip own block's), all 8 batches = 64B line
            const int idx = tid - 128;
            const int pu  = idx + (idx >= j * UPB ? UPB : 0);
            const unsigned want = (unsigned)(t + 1);
            const size_t base = (size_t)p * UNITS * BATCH + (size_t)pu * BATCH + gr * BPG;
            unsigned long long v0, v1, v2, v3, v4, v5, v6, v7;
            for (;;) {
                v0 = __hip_atomic_load(&hbuf[base + 0], __ATOMIC_RELAXED, __HIP_MEMORY_SCOPE_AGENT);
                v1 = __hip_atomic_load(&hbuf[base + 1], __ATOMIC_RELAXED, __HIP_MEMORY_SCOPE_AGENT);
                v2 = __hip_atomic_load(&hbuf[base + 2], __ATOMIC_RELAXED, __HIP_MEMORY_SCOPE_AGENT);
                v3 = __hip_atomic_load(&hbuf[base + 3], __ATOMIC_RELAXED, __HIP_MEMORY_SCOPE_AGENT);
                v4 = __hip_atomic_load(&hbuf[base + 4], __ATOMIC_RELAXED, __HIP_MEMORY_SCOPE_AGENT);
                v5 = __hip_atomic_load(&hbuf[base + 5], __ATOMIC_RELAXED, __HIP_MEMORY_SCOPE_AGENT);
                v6 = __hip_atomic_load(&hbuf[base + 6], __ATOMIC_RELAXED, __HIP_MEMORY_SCOPE_AGENT);
                v7 = __hip_atomic_load(&hbuf[base + 7], __ATOMIC_RELAXED, __HIP_MEMORY_SCOPE_AGENT);
                const unsigned ok =
                    ((unsigned)(v0 >> 32) == want) & ((unsigned)(v1 >> 32) == want) &
                    ((unsigned)(v2 >> 32) == want) & ((unsigned)(v3 >> 32) == want) &
                    ((unsigned)(v4 >> 32) == want) & ((unsigned)(v5 >> 32) == want) &
                    ((unsigned)(v6 >> 32) == want) & ((unsigned)(v7 >> 32) == want);
                if (ok) break;
                __builtin_amdgcn_s_sleep(2);
            }
            hsh[0][pu] = __uint_as_float((unsigned)v0);
            hsh[1][pu] = __uint_as_float((unsigned)v1);
            hsh[2][pu] = __uint_as_float((unsigned)v2);
            hsh[3][pu] = __uint_as_float((unsigned)v3);
            hsh[4][pu] = __uint_as_float((unsigned)v4);
            hsh[5][pu] = __uint_as_float((unsigned)v5);
            hsh[6][pu] = __uint_as_float((unsigned)v6);
            hsh[7][pu] = __uint_as_float((unsigned)v7);
        }
        __syncthreads();   // hsh = h_{t+1} complete
    }

    // ---- epilogue: y for final step ----
    if (tid >= 400 && tid < 412 && j < BPG) {
        const int f = (tid - 400) >> 2, ch = (tid - 400) & 3;
        float s = 0.f;
        const int u0 = ch * 100;
        #pragma unroll 4
        for (int u = u0; u < u0 + 100; ++u)
            s += hsh[j][u] * wosh[u][f];
        yred[f][ch] = s;
    }
    __syncthreads();
    if (tid < 3 && j < BPG)
        out[((size_t)(gr * BPG + j) * TLEN + (TLEN - 1)) * 3 + tid] =
            b_out[tid] + yred[tid][0] + yred[tid][1] + yred[tid][2] + yred[tid][3];
#undef ZFMA
}

// ---- fallback: proven round-1 single-block-per-batch kernel ----
__global__ __launch_bounds__(512) void lstm_fused_fb(
    const float* __restrict__ x, const float* __restrict__ W_x,
    const float* __restrict__ W_h, const float* __restrict__ bvec,
    const float* __restrict__ p_i, const float* __restrict__ p_f,
    const float* __restrict__ p_o, const float* __restrict__ W_out,
    const float* __restrict__ b_out, float* __restrict__ out)
{
    const int b = blockIdx.x, tid = threadIdx.x;
    const int lane = tid & 63, wv = tid >> 6;
    __shared__ float hsh[UNITS], csh[UNITS], zsh[GATES], xb[3], red[8][3];
    const float4* Wh4 = (const float4*)W_h;
    const int g = tid;
    float4 wx0, wx1, wx2, bb;
    if (g < GATES/4) {
        const float4* Wx4 = (const float4*)W_x;
        wx0 = Wx4[0*400 + g]; wx1 = Wx4[1*400 + g]; wx2 = Wx4[2*400 + g];
        bb  = ((const float4*)bvec)[g];
    }
    float piu=0.f,pfu=0.f,pou=0.f,wo0=0.f,wo1=0.f,wo2=0.f;
    if (tid < UNITS) {
        piu=p_i[tid]; pfu=p_f[tid]; pou=p_o[tid];
        wo0=W_out[tid*3]; wo1=W_out[tid*3+1]; wo2=W_out[tid*3+2];
        hsh[tid]=0.f; csh[tid]=0.f;
    }
    const float bo = (tid<3)?b_out[tid]:0.f;
    const float* xrow = x + (size_t)b*TLEN*3;
    float* orow = out + (size_t)b*TLEN*3;
    for (int t=0;t<TLEN;++t){
        if (tid<3) xb[tid]=xrow[t*3+tid];
        __syncthreads();
        const float x0=xb[0],x1=xb[1],x2=xb[2];
        if (g < GATES/4){
            float4 acc;
            acc.x=fmaf(x0,wx0.x,fmaf(x1,wx1.x,fmaf(x2,wx2.x,bb.x)));
            acc.y=fmaf(x0,wx0.y,fmaf(x1,wx1.y,fmaf(x2,wx2.y,bb.y)));
            acc.z=fmaf(x0,wx0.z,fmaf(x1,wx1.z,fmaf(x2,wx2.z,bb.z)));
            acc.w=fmaf(x0,wx0.w,fmaf(x1,wx1.w,fmaf(x2,wx2.w,bb.w)));
            const float4* wp=Wh4+g;
            #pragma unroll 8
            for(int k=0;k<UNITS;++k){
                const float hk=hsh[k]; const float4 w=wp[(size_t)k*400];
                acc.x=fmaf(hk,w.x,acc.x); acc.y=fmaf(hk,w.y,acc.y);
                acc.z=fmaf(hk,w.z,acc.z); acc.w=fmaf(hk,w.w,acc.w);
            }
            ((float4*)zsh)[g]=acc;
        }
        __syncthreads();
        float s0=0.f,s1=0.f,s2=0.f;
        if (tid<UNITS){
            const float cc=csh[tid];
            const float zi=zsh[tid],zf=zsh[tid+UNITS],zg=zsh[tid+2*UNITS],zo=zsh[tid+3*UNITS];
            const float ig=sigmoid_(fmaf(piu,cc,zi));
            const float fg=sigmoid_(fmaf(pfu,cc,zf));
            const float gg=tanh_(zg);
            const float cn=fmaf(fg,cc,ig*gg);
            const float og=sigmoid_(fmaf(pou,cn,zo));
            const float hn=og*tanh_(cn);
            csh[tid]=cn; hsh[tid]=hn;
            s0=hn*wo0; s1=hn*wo1; s2=hn*wo2;
        }
        #pragma unroll
        for(int off=32;off;off>>=1){
            s0+=__shfl_down(s0,off); s1+=__shfl_down(s1,off); s2+=__shfl_down(s2,off);
        }
        if(lane==0){red[wv][0]=s0;red[wv][1]=s1;red[wv][2]=s2;}
        __syncthreads();
        if(tid<3){
            float r=bo;
            #pragma unroll
            for(int w2=0;w2<8;++w2) r+=red[w2][tid];
            orow[t*3+tid]=r;
        }
    }
}

extern "C" void kernel_launch(void* const* d_in, const int* in_sizes, int n_in,
                              void* d_out, int out_size, void* d_ws, size_t ws_size,
                              hipStream_t stream) {
    const float* x     = (const float*)d_in[0];
    const float* W_x   = (const float*)d_in[1];
    const float* W_h   = (const float*)d_in[2];
    const float* b     = (const float*)d_in[3];
    const float* p_i   = (const float*)d_in[4];
    const float* p_f   = (const float*)d_in[5];
    const float* p_o   = (const float*)d_in[6];
    const float* W_out = (const float*)d_in[7];
    const float* b_out = (const float*)d_in[8];
    float* out = (float*)d_out;

    if (ws_size < WS_FULL) {
        lstm_fused_fb<<<BATCH, 512, 0, stream>>>(x, W_x, W_h, b, p_i, p_f, p_o,
                                                 W_out, b_out, out);
        return;
    }

    uint8_t* ws = (uint8_t*)d_ws;
    float* wbuf = (float*)(ws + WBUF_OFF);
    unsigned long long* hbuf = (unsigned long long*)(ws + HBUF_OFF);

    hipMemsetAsync(hbuf, 0, HBUF_SZ, stream);    // kill stale tags (graph replay)
    reorder_w<<<(NBLK * UNITS * CPB + 255) / 256, 256, 0, stream>>>(W_h, wbuf);
    lstm_mb<<<NGRP * NBLK, 512, 0, stream>>>(x, W_x, b, p_i, p_f, p_o,
                                             W_out, b_out, wbuf, hbuf, out);
}